// Round 1
// baseline (1352.396 us; speedup 1.0000x reference)
//
#include <hip/hip_runtime.h>

// Problem constants (match reference)
constexpr int NB = 128, NN = 1024, ND = 512, NL = 3, NK = 256;
constexpr int ROWS = NB * NN;            // 131072

// Tiling
#define TM 32
#define KC 16

// Workspace layout (float offsets)
constexpr int CSQ_OFF = 0;                          // 768 floats
constexpr int CT_OFF  = 1024;                       // 3*512*256 = 393216
constexpr int G01_OFF = CT_OFF + NL * ND * NK;      // 394240
constexpr int G02_OFF = G01_OFF + NK * NK;          // 459776
constexpr int G12_OFF = G02_OFF + NK * NK;          // 525312
// total = 590848 floats = ~2.26 MB

// ---------------------------------------------------------------------------
// Kernel 1: per-centroid squared norms + transposed codebook CT[l][d][k]
// one wave per centroid (768 waves)
__global__ __launch_bounds__(256) void prep_kernel(const float* __restrict__ C,
                                                   float* __restrict__ ws) {
    int wid  = blockIdx.x * 4 + (threadIdx.x >> 6);   // 0..767 = l*256+k
    int lane = threadIdx.x & 63;
    const float4* src = reinterpret_cast<const float4*>(C + (size_t)wid * ND + lane * 8);
    float4 c0 = src[0];
    float4 c1 = src[1];
    float sq = c0.x*c0.x + c0.y*c0.y + c0.z*c0.z + c0.w*c0.w
             + c1.x*c1.x + c1.y*c1.y + c1.z*c1.z + c1.w*c1.w;
    #pragma unroll
    for (int m = 1; m < 64; m <<= 1) sq += __shfl_xor(sq, m, 64);
    if (lane == 0) ws[CSQ_OFF + wid] = sq;

    int l = wid >> 8, k = wid & 255;
    float* ct = ws + CT_OFF + (size_t)l * ND * NK + k;
    int d0 = lane * 8;
    ct[(size_t)(d0 + 0) * NK] = c0.x;
    ct[(size_t)(d0 + 1) * NK] = c0.y;
    ct[(size_t)(d0 + 2) * NK] = c0.z;
    ct[(size_t)(d0 + 3) * NK] = c0.w;
    ct[(size_t)(d0 + 4) * NK] = c1.x;
    ct[(size_t)(d0 + 5) * NK] = c1.y;
    ct[(size_t)(d0 + 6) * NK] = c1.z;
    ct[(size_t)(d0 + 7) * NK] = c1.w;
}

// ---------------------------------------------------------------------------
// Kernel 2: Gram matrices G01, G02, G12 (256x256 each)
// grid = 3*256 blocks; block (p, i); thread j computes G[i][j]
__global__ __launch_bounds__(256) void gram_kernel(const float* __restrict__ C,
                                                   float* __restrict__ ws) {
    int p = blockIdx.x >> 8;       // 0:(0,1) 1:(0,2) 2:(1,2)
    int i = blockIdx.x & 255;
    int a = (p == 2) ? 1 : 0;
    int b = (p == 0) ? 1 : 2;
    const float* Ca  = C + ((size_t)a * NK + i) * ND;
    const float* CTb = ws + CT_OFF + (size_t)b * ND * NK;
    int j = threadIdx.x;
    float s = 0.f;
    for (int d = 0; d < ND; d += 4) {
        float4 ca = *reinterpret_cast<const float4*>(Ca + d);
        s = fmaf(ca.x, CTb[(size_t)(d + 0) * NK + j], s);
        s = fmaf(ca.y, CTb[(size_t)(d + 1) * NK + j], s);
        s = fmaf(ca.z, CTb[(size_t)(d + 2) * NK + j], s);
        s = fmaf(ca.w, CTb[(size_t)(d + 3) * NK + j], s);
    }
    float* G = ws + ((p == 0) ? G01_OFF : (p == 1) ? G02_OFF : G12_OFF);
    G[(size_t)i * NK + j] = s;
}

// ---------------------------------------------------------------------------
// Kernel 3: fused GEMM + argmin cascade + gather
// block = 256 threads, tile = TM(32) rows x 256 centroids, per layer
__global__ __launch_bounds__(256) void rq_main(const float* __restrict__ X,
                                               const float* __restrict__ C,
                                               const float* __restrict__ ws,
                                               float* __restrict__ out) {
    __shared__ float As[TM][KC];        // 2 KB
    __shared__ float Bs[KC][NK];        // 16 KB
    __shared__ float redS[TM][33];      // 4.1 KB
    __shared__ int   redI[TM][33];      // 4.1 KB
    __shared__ int   isel[NL][TM];

    const int tid  = threadIdx.x;
    const int trow = tid >> 5;          // 0..7  -> rows 4*trow..4*trow+3
    const int tcol = tid & 31;          // 0..31 -> cols {4t..4t+3} u {128+4t..}
    const int row0 = blockIdx.x * TM;

    const float* csq = ws + CSQ_OFF;
    const float* CT  = ws + CT_OFF;
    const float* G01 = ws + G01_OFF;
    const float* G02 = ws + G02_OFF;
    const float* G12 = ws + G12_OFF;

    for (int l = 0; l < NL; ++l) {
        float acc[4][8];
        #pragma unroll
        for (int i = 0; i < 4; ++i)
            #pragma unroll
            for (int j = 0; j < 8; ++j) acc[i][j] = 0.f;

        const float* CTl = CT + (size_t)l * ND * NK;

        for (int kc = 0; kc < ND; kc += KC) {
            // stage As (32x16): 256 threads x float2
            {
                int r  = tid >> 3;
                int kk = (tid & 7) * 2;
                float2 v = *reinterpret_cast<const float2*>(
                    X + (size_t)(row0 + r) * ND + kc + kk);
                *reinterpret_cast<float2*>(&As[r][kk]) = v;
            }
            // stage Bs (16x256): 1024 float4, 4 per thread
            #pragma unroll
            for (int q = 0; q < 4; ++q) {
                int idx = tid + 256 * q;
                int k   = idx >> 6;
                int c4  = (idx & 63) * 4;
                float4 v = *reinterpret_cast<const float4*>(
                    CTl + (size_t)(kc + k) * NK + c4);
                *reinterpret_cast<float4*>(&Bs[k][c4]) = v;
            }
            __syncthreads();

            #pragma unroll
            for (int k4 = 0; k4 < KC; k4 += 4) {
                float4 a[4];
                #pragma unroll
                for (int i = 0; i < 4; ++i)
                    a[i] = *reinterpret_cast<const float4*>(&As[4 * trow + i][k4]);
                #pragma unroll
                for (int kk = 0; kk < 4; ++kk) {
                    float4 b0 = *reinterpret_cast<const float4*>(&Bs[k4 + kk][4 * tcol]);
                    float4 b1 = *reinterpret_cast<const float4*>(&Bs[k4 + kk][128 + 4 * tcol]);
                    #pragma unroll
                    for (int i = 0; i < 4; ++i) {
                        float av = (kk == 0) ? a[i].x : (kk == 1) ? a[i].y
                                 : (kk == 2) ? a[i].z : a[i].w;
                        acc[i][0] = fmaf(av, b0.x, acc[i][0]);
                        acc[i][1] = fmaf(av, b0.y, acc[i][1]);
                        acc[i][2] = fmaf(av, b0.z, acc[i][2]);
                        acc[i][3] = fmaf(av, b0.w, acc[i][3]);
                        acc[i][4] = fmaf(av, b1.x, acc[i][4]);
                        acc[i][5] = fmaf(av, b1.y, acc[i][5]);
                        acc[i][6] = fmaf(av, b1.z, acc[i][6]);
                        acc[i][7] = fmaf(av, b1.w, acc[i][7]);
                    }
                }
            }
            __syncthreads();
        }

        // scoring + per-thread local argmin (first-index tie-break)
        #pragma unroll
        for (int i = 0; i < 4; ++i) {
            int lrow = 4 * trow + i;
            int ia = 0, ib = 0;
            if (l >= 1) ia = isel[0][lrow];
            if (l == 2) ib = isel[1][lrow];
            float bsv = 3.4e38f;
            int   bki = 0;
            #pragma unroll
            for (int j = 0; j < 8; ++j) {
                int c = (j < 4) ? (4 * tcol + j) : (128 + 4 * tcol + (j - 4));
                float s = csq[l * NK + c] - 2.f * acc[i][j];
                if (l == 1) s += 2.f * G01[(size_t)ia * NK + c];
                if (l == 2) s += 2.f * (G02[(size_t)ia * NK + c] +
                                        G12[(size_t)ib * NK + c]);
                if (s < bsv || (s == bsv && c < bki)) { bsv = s; bki = c; }
            }
            redS[lrow][tcol] = bsv;
            redI[lrow][tcol] = bki;
        }
        __syncthreads();
        if (tid < TM) {
            float bsv = redS[tid][0];
            int   bki = redI[tid][0];
            #pragma unroll 4
            for (int t = 1; t < 32; ++t) {
                float s = redS[tid][t];
                int   k = redI[tid][t];
                if (s < bsv || (s == bsv && k < bki)) { bsv = s; bki = k; }
            }
            isel[l][tid] = bki;
        }
        __syncthreads();
    }

    // write ids (as float; values 0..255 exact)
    if (tid < TM * 3) {
        int r = tid / 3, l = tid % 3;
        out[(size_t)(row0 + r) * 3 + l] = (float)isel[l][r];
    }

    // write reconstruction = sum of 3 selected centroids (L2-hot gather)
    float* rec = out + (size_t)ROWS * 3;
    #pragma unroll
    for (int q = 0; q < 16; ++q) {
        int idx = tid + 256 * q;          // 0..4095
        int r   = idx >> 7;               // 128 float4 per row
        int d4  = (idx & 127) * 4;
        int j0 = isel[0][r], j1 = isel[1][r], j2 = isel[2][r];
        float4 v0 = *reinterpret_cast<const float4*>(C + ((size_t)0 * NK + j0) * ND + d4);
        float4 v1 = *reinterpret_cast<const float4*>(C + ((size_t)1 * NK + j1) * ND + d4);
        float4 v2 = *reinterpret_cast<const float4*>(C + ((size_t)2 * NK + j2) * ND + d4);
        float4 o;
        o.x = v0.x + v1.x + v2.x;
        o.y = v0.y + v1.y + v2.y;
        o.z = v0.z + v1.z + v2.z;
        o.w = v0.w + v1.w + v2.w;
        *reinterpret_cast<float4*>(rec + (size_t)(row0 + r) * ND + d4) = o;
    }
}

// ---------------------------------------------------------------------------
extern "C" void kernel_launch(void* const* d_in, const int* in_sizes, int n_in,
                              void* d_out, int out_size, void* d_ws, size_t ws_size,
                              hipStream_t stream) {
    const float* X  = (const float*)d_in[0];   // [128,1024,512]
    const float* C  = (const float*)d_in[1];   // [3,256,512]
    float*       ws = (float*)d_ws;
    float*       out = (float*)d_out;

    hipLaunchKernelGGL(prep_kernel, dim3(NL * NK / 4), dim3(256), 0, stream, C, ws);
    hipLaunchKernelGGL(gram_kernel, dim3(NL * NK), dim3(256), 0, stream, C, ws);
    hipLaunchKernelGGL(rq_main, dim3(ROWS / TM), dim3(256), 0, stream, X, C, ws, out);
}

// Round 2
// 930.922 us; speedup vs baseline: 1.4527x; 1.4527x over previous
//
#include <hip/hip_runtime.h>

typedef unsigned short u16;
typedef short s8v __attribute__((ext_vector_type(8)));   // 8 bf16 in 4 VGPRs
typedef float f4  __attribute__((ext_vector_type(4)));   // MFMA acc

constexpr int ND = 512, NL = 3, NK = 256;
constexpr int ROWS = 128 * 1024;
#define TM 32
#define DELTA 0.05f

// ---- workspace layout ----
// float region
constexpr int CSQ_OFF = 0;                    // 768 floats
constexpr int G01_OFF = 1024;
constexpr int G02_OFF = G01_OFF + 65536;
constexpr int G12_OFF = G02_OFF + 65536;
constexpr int WS_FLOATS = G12_OFF + 65536;    // 197632 floats
// bf16 (ushort) region: Bg tiles [3][16 kt][16 ct][64 lanes * 8] (1KB tiles)
constexpr int BGH_OFF_US = WS_FLOATS * 2;     // ushort offset
constexpr int BG_TILES   = 3 * 16 * 16;       // 768
constexpr int BGL_OFF_US = BGH_OFF_US + BG_TILES * 512;
// total bytes = (BGL_OFF_US + BG_TILES*512)*2 = 2,363,392 (same as round-1 usage)

__device__ __forceinline__ u16 f2bf(float f) {          // fp32 -> bf16 RNE
    unsigned u = __float_as_uint(f);
    return (u16)((u + 0x7fffu + ((u >> 16) & 1u)) >> 16);
}
__device__ __forceinline__ float bf2f(u16 h) {
    return __uint_as_float(((unsigned)h) << 16);
}

// ---------------------------------------------------------------------------
// csq[768]: one wave per centroid
__global__ __launch_bounds__(256) void prep_csq(const float* __restrict__ C,
                                                float* __restrict__ ws) {
    int wid  = blockIdx.x * 4 + (threadIdx.x >> 6);   // 0..767
    int lane = threadIdx.x & 63;
    const float4* src = reinterpret_cast<const float4*>(C + (size_t)wid * ND + lane * 8);
    float4 a = src[0], b = src[1];
    float sq = a.x*a.x + a.y*a.y + a.z*a.z + a.w*a.w
             + b.x*b.x + b.y*b.y + b.z*b.z + b.w*b.w;
    #pragma unroll
    for (int m = 1; m < 64; m <<= 1) sq += __shfl_xor(sq, m, 64);
    if (lane == 0) ws[CSQ_OFF + wid] = sq;
}

// ---------------------------------------------------------------------------
// Bg: codebooks -> bf16 hi/lo, pre-arranged in MFMA B-fragment tile order.
// tile wid = l*256 + kt*16 + ct; lane slot holds n=ct*16+(lane&15),
// k = kt*32 + (lane>>4)*8 + j  (j=0..7, 2B each)
__global__ __launch_bounds__(256) void prep_b(const float* __restrict__ C,
                                              u16* __restrict__ wsu) {
    int wid  = blockIdx.x * 4 + (threadIdx.x >> 6);   // 0..767
    int lane = threadIdx.x & 63;
    int l  = wid >> 8, kt = (wid >> 4) & 15, ct = wid & 15;
    int n  = ct * 16 + (lane & 15);
    int k0 = kt * 32 + (lane >> 4) * 8;
    const float* src = C + ((size_t)l * NK + n) * ND + k0;
    float4 xa = *reinterpret_cast<const float4*>(src);
    float4 xb = *reinterpret_cast<const float4*>(src + 4);
    float x[8] = {xa.x, xa.y, xa.z, xa.w, xb.x, xb.y, xb.z, xb.w};
    unsigned hp[4], lp[4];
    #pragma unroll
    for (int q = 0; q < 4; ++q) {
        u16 h0 = f2bf(x[2*q]), h1 = f2bf(x[2*q+1]);
        u16 l0 = f2bf(x[2*q]   - bf2f(h0));
        u16 l1 = f2bf(x[2*q+1] - bf2f(h1));
        hp[q] = (unsigned)h0 | ((unsigned)h1 << 16);
        lp[q] = (unsigned)l0 | ((unsigned)l1 << 16);
    }
    uint4 hv = {hp[0], hp[1], hp[2], hp[3]};
    uint4 lv = {lp[0], lp[1], lp[2], lp[3]};
    *reinterpret_cast<uint4*>(wsu + BGH_OFF_US + (size_t)wid * 512 + lane * 8) = hv;
    *reinterpret_cast<uint4*>(wsu + BGL_OFF_US + (size_t)wid * 512 + lane * 8) = lv;
}

// ---------------------------------------------------------------------------
// Gram matrices (fp32 exact): block per (p, i), thread j -> G_p[i][j]
__global__ __launch_bounds__(256) void gram_kernel(const float* __restrict__ C,
                                                   float* __restrict__ ws) {
    int p = blockIdx.x >> 8;       // 0:(0,1) 1:(0,2) 2:(1,2)
    int i = blockIdx.x & 255;
    int a = (p == 2) ? 1 : 0;
    int b = (p == 0) ? 1 : 2;
    __shared__ float Ca[512];
    float2 v = *reinterpret_cast<const float2*>(C + ((size_t)a * NK + i) * ND + threadIdx.x * 2);
    Ca[threadIdx.x * 2]     = v.x;
    Ca[threadIdx.x * 2 + 1] = v.y;
    __syncthreads();
    int j = threadIdx.x;
    const float* Cb = C + ((size_t)b * NK + j) * ND;
    float s = 0.f;
    for (int d = 0; d < 512; d += 8) {
        float4 u = *reinterpret_cast<const float4*>(Cb + d);
        float4 w = *reinterpret_cast<const float4*>(Cb + d + 4);
        s = fmaf(u.x, Ca[d+0], s); s = fmaf(u.y, Ca[d+1], s);
        s = fmaf(u.z, Ca[d+2], s); s = fmaf(u.w, Ca[d+3], s);
        s = fmaf(w.x, Ca[d+4], s); s = fmaf(w.y, Ca[d+5], s);
        s = fmaf(w.z, Ca[d+6], s); s = fmaf(w.w, Ca[d+7], s);
    }
    float* G = ws + ((p == 0) ? G01_OFF : (p == 1) ? G02_OFF : G12_OFF);
    G[(size_t)i * NK + j] = s;
}

// ---------------------------------------------------------------------------
// Main: 32-row tile x 768 cols, bf16-split MFMA + cascade argmin + refine
__global__ __launch_bounds__(256, 2) void rq_mfma(const float* __restrict__ X,
                                                  const float* __restrict__ C,
                                                  const float* __restrict__ ws,
                                                  const u16* __restrict__ wsu,
                                                  float* __restrict__ out) {
    __shared__ __align__(16) u16 Ah[2 * 512];     // 2KB  (A-frag tiles, rt=0,1)
    __shared__ __align__(16) u16 Al[2 * 512];     // 2KB
    __shared__ __align__(16) u16 Bs[48 * 512];    // 48KB (B-frag tiles T=0..47)
    __shared__ float redV[4][32];
    __shared__ int   redI[4][32];
    __shared__ float mrow[32];
    __shared__ int   iseltmp[32];
    __shared__ int   isel[3][32];                  // LOCAL ids 0..255
    __shared__ int   ccnt[32];
    __shared__ int   ntask;
    __shared__ int   taskRC[96];                   // (row<<10)|global_col
    __shared__ float taskS[96];

    const int tid  = threadIdx.x;
    const int w    = tid >> 6;
    const int lane = tid & 63;
    const int hi4  = lane >> 4, l15 = lane & 15;
    const int row0 = blockIdx.x * TM;

    const float* csq = ws + CSQ_OFF;
    const float* G01 = ws + G01_OFF;
    const float* G02 = ws + G02_OFF;
    const float* G12 = ws + G12_OFF;

    f4 acc[2][12];
    #pragma unroll
    for (int rt = 0; rt < 2; ++rt)
        #pragma unroll
        for (int ft = 0; ft < 12; ++ft) acc[rt][ft] = (f4){0.f, 0.f, 0.f, 0.f};

    // A staging geometry: thread -> (row, 4 consecutive k)
    const int arow = tid >> 3;          // 0..31
    const int a7   = tid & 7;           // k4 = a7*4 within the 32-k chunk
    const int a_slot = (arow & 15) + 16 * (a7 >> 1);
    const int a_off  = (arow >> 4) * 512 + a_slot * 8 + (a7 & 1) * 4;  // ushorts

    for (int pass = 0; pass < 2; ++pass) {
        const u16* Bg = wsu + (pass == 0 ? BGH_OFF_US : BGL_OFF_US);
        for (int kt = 0; kt < 16; ++kt) {
            // ---- stage A chunk (convert fp32 -> bf16 hi[/lo]) ----
            {
                const float* xp = X + (size_t)(row0 + arow) * ND + kt * 32 + a7 * 4;
                float4 xv = *reinterpret_cast<const float4*>(xp);
                u16 h0 = f2bf(xv.x), h1 = f2bf(xv.y), h2 = f2bf(xv.z), h3 = f2bf(xv.w);
                uint2 hv = {(unsigned)h0 | ((unsigned)h1 << 16),
                            (unsigned)h2 | ((unsigned)h3 << 16)};
                *reinterpret_cast<uint2*>(Ah + a_off) = hv;
                if (pass == 0) {
                    u16 q0 = f2bf(xv.x - bf2f(h0)), q1 = f2bf(xv.y - bf2f(h1));
                    u16 q2 = f2bf(xv.z - bf2f(h2)), q3 = f2bf(xv.w - bf2f(h3));
                    uint2 lv = {(unsigned)q0 | ((unsigned)q1 << 16),
                                (unsigned)q2 | ((unsigned)q3 << 16)};
                    *reinterpret_cast<uint2*>(Al + a_off) = lv;
                }
            }
            // ---- stage B tiles (reg staging, 12 tiles per wave) ----
            #pragma unroll
            for (int j = 0; j < 12; ++j) {
                int T = w * 12 + j;
                const u16* src = Bg + (size_t)((T >> 4) * 256 + kt * 16 + (T & 15)) * 512 + lane * 8;
                uint4 v = *reinterpret_cast<const uint4*>(src);
                *reinterpret_cast<uint4*>(Bs + T * 512 + lane * 8) = v;
            }
            __syncthreads();
            // ---- MFMA ----
            s8v ah0 = *reinterpret_cast<const s8v*>(Ah + 0 * 512 + lane * 8);
            s8v ah1 = *reinterpret_cast<const s8v*>(Ah + 1 * 512 + lane * 8);
            s8v al0, al1;
            if (pass == 0) {
                al0 = *reinterpret_cast<const s8v*>(Al + 0 * 512 + lane * 8);
                al1 = *reinterpret_cast<const s8v*>(Al + 1 * 512 + lane * 8);
            }
            #pragma unroll
            for (int ft = 0; ft < 12; ++ft) {
                int T = w + 4 * ft;
                s8v b = *reinterpret_cast<const s8v*>(Bs + T * 512 + lane * 8);
                acc[0][ft] = __builtin_amdgcn_mfma_f32_16x16x32_bf16(ah0, b, acc[0][ft], 0, 0, 0);
                acc[1][ft] = __builtin_amdgcn_mfma_f32_16x16x32_bf16(ah1, b, acc[1][ft], 0, 0, 0);
                if (pass == 0) {
                    acc[0][ft] = __builtin_amdgcn_mfma_f32_16x16x32_bf16(al0, b, acc[0][ft], 0, 0, 0);
                    acc[1][ft] = __builtin_amdgcn_mfma_f32_16x16x32_bf16(al1, b, acc[1][ft], 0, 0, 0);
                }
            }
            __syncthreads();
        }
    }

    // ---- cascade: per layer argmin (+ exact refine of near-ties) ----
    #pragma unroll
    for (int l = 0; l < NL; ++l) {
        if (tid < 32) ccnt[tid] = 0;
        if (tid == 0) ntask = 0;

        float bv[2][4]; int bi[2][4];
        #pragma unroll
        for (int rt = 0; rt < 2; ++rt)
            #pragma unroll
            for (int reg = 0; reg < 4; ++reg) { bv[rt][reg] = 3.4e38f; bi[rt][reg] = 0x7fffffff; }

        #pragma unroll
        for (int rt = 0; rt < 2; ++rt)
            #pragma unroll
            for (int f = 0; f < 4; ++f) {
                const int ft  = l * 4 + f;
                const int T   = w + 4 * ft;
                const int col = l * 256 + (T & 15) * 16 + l15;   // global col
                #pragma unroll
                for (int reg = 0; reg < 4; ++reg) {
                    const int row = rt * 16 + hi4 * 4 + reg;
                    float s = csq[col] - 2.f * acc[rt][ft][reg];
                    if (l == 1) {
                        int i0 = isel[0][row];
                        s += 2.f * G01[(size_t)i0 * NK + (col & 255)];
                    }
                    if (l == 2) {
                        int i0 = isel[0][row], i1 = isel[1][row];
                        s += 2.f * (G02[(size_t)i0 * NK + (col & 255)] +
                                    G12[(size_t)i1 * NK + (col & 255)]);
                    }
                    if (s < bv[rt][reg] || (s == bv[rt][reg] && col < bi[rt][reg])) {
                        bv[rt][reg] = s; bi[rt][reg] = col;
                    }
                }
            }
        // reduce across the 16-lane col groups
        #pragma unroll
        for (int rt = 0; rt < 2; ++rt)
            #pragma unroll
            for (int reg = 0; reg < 4; ++reg) {
                float v = bv[rt][reg]; int ix = bi[rt][reg];
                #pragma unroll
                for (int m = 1; m < 16; m <<= 1) {
                    float v2 = __shfl_xor(v, m, 64);
                    int   i2 = __shfl_xor(ix, m, 64);
                    if (v2 < v || (v2 == v && i2 < ix)) { v = v2; ix = i2; }
                }
                if (l15 == 0) {
                    int row = rt * 16 + hi4 * 4 + reg;
                    redV[w][row] = v; redI[w][row] = ix;
                }
            }
        __syncthreads();
        if (tid < 32) {
            float v = redV[0][tid]; int ix = redI[0][tid];
            #pragma unroll
            for (int q = 1; q < 4; ++q) {
                float v2 = redV[q][tid]; int i2 = redI[q][tid];
                if (v2 < v || (v2 == v && i2 < ix)) { v = v2; ix = i2; }
            }
            mrow[tid] = v; iseltmp[tid] = ix;
        }
        __syncthreads();
        // candidate scan (recompute scores, append near-ties)
        #pragma unroll
        for (int rt = 0; rt < 2; ++rt)
            #pragma unroll
            for (int f = 0; f < 4; ++f) {
                const int ft  = l * 4 + f;
                const int T   = w + 4 * ft;
                const int col = l * 256 + (T & 15) * 16 + l15;
                #pragma unroll
                for (int reg = 0; reg < 4; ++reg) {
                    const int row = rt * 16 + hi4 * 4 + reg;
                    float s = csq[col] - 2.f * acc[rt][ft][reg];
                    if (l == 1) {
                        int i0 = isel[0][row];
                        s += 2.f * G01[(size_t)i0 * NK + (col & 255)];
                    }
                    if (l == 2) {
                        int i0 = isel[0][row], i1 = isel[1][row];
                        s += 2.f * (G02[(size_t)i0 * NK + (col & 255)] +
                                    G12[(size_t)i1 * NK + (col & 255)]);
                    }
                    if (s <= mrow[row] + DELTA) {
                        atomicAdd(&ccnt[row], 1);
                        int t = atomicAdd(&ntask, 1);
                        if (t < 96) taskRC[t] = (row << 10) | col;
                    }
                }
            }
        __syncthreads();
        // exact refine for rows with >=2 candidates (full-wave fp32 dot)
        {
            int nt = ntask < 96 ? ntask : 96;
            for (int ti = w; ti < nt; ti += 4) {
                int rc = taskRC[ti];
                int row = rc >> 10, col = rc & 1023;
                if (ccnt[row] >= 2) {
                    const float* xr = X + (size_t)(row0 + row) * ND + lane * 8;
                    const float* cr = C + (size_t)col * ND + lane * 8;
                    float4 xa = *reinterpret_cast<const float4*>(xr);
                    float4 xb = *reinterpret_cast<const float4*>(xr + 4);
                    float4 ca = *reinterpret_cast<const float4*>(cr);
                    float4 cb = *reinterpret_cast<const float4*>(cr + 4);
                    float d = xa.x*ca.x + xa.y*ca.y + xa.z*ca.z + xa.w*ca.w
                            + xb.x*cb.x + xb.y*cb.y + xb.z*cb.z + xb.w*cb.w;
                    #pragma unroll
                    for (int m = 1; m < 64; m <<= 1) d += __shfl_xor(d, m, 64);
                    if (lane == 0) {
                        float sc = csq[col] - 2.f * d;
                        if (l == 1) sc += 2.f * G01[(size_t)isel[0][row] * NK + (col & 255)];
                        if (l == 2) sc += 2.f * (G02[(size_t)isel[0][row] * NK + (col & 255)] +
                                                 G12[(size_t)isel[1][row] * NK + (col & 255)]);
                        taskS[ti] = sc;
                    }
                }
            }
        }
        __syncthreads();
        if (tid < 32) {
            int best;
            if (ccnt[tid] >= 2) {
                float bvv = 3.4e38f; int bii = iseltmp[tid];
                int nt = ntask < 96 ? ntask : 96;
                for (int t = 0; t < nt; ++t) {
                    int rc = taskRC[t];
                    if ((rc >> 10) == tid) {
                        float s = taskS[t]; int c = rc & 1023;
                        if (s < bvv || (s == bvv && c < bii)) { bvv = s; bii = c; }
                    }
                }
                best = bii;
            } else {
                best = iseltmp[tid];
            }
            isel[l][tid] = best & 255;     // store LOCAL id
        }
        __syncthreads();
    }

    // ---- outputs ----
    if (tid < TM * 3) {
        int r = tid / 3, l = tid % 3;
        out[(size_t)(row0 + r) * 3 + l] = (float)isel[l][r];
    }
    float* rec = out + (size_t)ROWS * 3;
    #pragma unroll
    for (int q = 0; q < 16; ++q) {
        int idx = tid + 256 * q;          // 0..4095
        int r   = idx >> 7;
        int d4  = (idx & 127) * 4;
        float4 v0 = *reinterpret_cast<const float4*>(C + ((size_t)(  0 + isel[0][r])) * ND + d4);
        float4 v1 = *reinterpret_cast<const float4*>(C + ((size_t)(256 + isel[1][r])) * ND + d4);
        float4 v2 = *reinterpret_cast<const float4*>(C + ((size_t)(512 + isel[2][r])) * ND + d4);
        float4 o;
        o.x = v0.x + v1.x + v2.x;
        o.y = v0.y + v1.y + v2.y;
        o.z = v0.z + v1.z + v2.z;
        o.w = v0.w + v1.w + v2.w;
        *reinterpret_cast<float4*>(rec + (size_t)(row0 + r) * ND + d4) = o;
    }
}

// ---------------------------------------------------------------------------
extern "C" void kernel_launch(void* const* d_in, const int* in_sizes, int n_in,
                              void* d_out, int out_size, void* d_ws, size_t ws_size,
                              hipStream_t stream) {
    const float* X  = (const float*)d_in[0];   // [128,1024,512]
    const float* C  = (const float*)d_in[1];   // [3,256,512]
    float* ws  = (float*)d_ws;
    u16*   wsu = (u16*)d_ws;
    float* out = (float*)d_out;

    hipLaunchKernelGGL(prep_csq,    dim3(192),       dim3(256), 0, stream, C, ws);
    hipLaunchKernelGGL(prep_b,      dim3(192),       dim3(256), 0, stream, C, wsu);
    hipLaunchKernelGGL(gram_kernel, dim3(768),       dim3(256), 0, stream, C, ws);
    hipLaunchKernelGGL(rq_mfma,     dim3(ROWS / TM), dim3(256), 0, stream,
                       X, C, ws, wsu, out);
}

// Round 3
// 871.107 us; speedup vs baseline: 1.5525x; 1.0687x over previous
//
#include <hip/hip_runtime.h>

typedef unsigned short u16;
typedef short s8v __attribute__((ext_vector_type(8)));   // 8 bf16 in 4 VGPRs
typedef float f4  __attribute__((ext_vector_type(4)));   // MFMA acc

constexpr int ND = 512, NL = 3, NK = 256;
constexpr int ROWS = 128 * 1024;
#define TM 64
#define DELTA 0.75f

// ---- workspace layout ----
constexpr int CSQ_OFF = 0;                    // 768 floats
constexpr int G01_OFF = 1024;
constexpr int G02_OFF = G01_OFF + 65536;
constexpr int G12_OFF = G02_OFF + 65536;
constexpr int WS_FLOATS = G12_OFF + 65536;    // 197632 floats
// bf16 fragment table: [kt=16][CT=48][512 ushorts] (1KB tiles, kt-major)
constexpr int BGH_OFF_US = WS_FLOATS * 2;     // ushort offset
// total bytes = 197632*4 + 768*512*2 = 1.58 MB

__device__ __forceinline__ u16 f2bf(float f) {          // fp32 -> bf16 RNE
    unsigned u = __float_as_uint(f);
    return (u16)((u + 0x7fffu + ((u >> 16) & 1u)) >> 16);
}

// ---------------------------------------------------------------------------
// csq[768]: one wave per centroid
__global__ __launch_bounds__(256) void prep_csq(const float* __restrict__ C,
                                                float* __restrict__ ws) {
    int wid  = blockIdx.x * 4 + (threadIdx.x >> 6);   // 0..767
    int lane = threadIdx.x & 63;
    const float4* src = reinterpret_cast<const float4*>(C + (size_t)wid * ND + lane * 8);
    float4 a = src[0], b = src[1];
    float sq = a.x*a.x + a.y*a.y + a.z*a.z + a.w*a.w
             + b.x*b.x + b.y*b.y + b.z*b.z + b.w*b.w;
    #pragma unroll
    for (int m = 1; m < 64; m <<= 1) sq += __shfl_xor(sq, m, 64);
    if (lane == 0) ws[CSQ_OFF + wid] = sq;
}

// ---------------------------------------------------------------------------
// B fragment table: bf16, MFMA B-frag layout, kt-major tiles.
// wid = l*256 + kt*16 + ct  ->  tile TI = kt*48 + l*16 + ct
// lane slot: col = ct*16 + (lane&15), k = kt*32 + (lane>>4)*8 + j (j=0..7)
__global__ __launch_bounds__(256) void prep_b(const float* __restrict__ C,
                                              u16* __restrict__ wsu) {
    int wid  = blockIdx.x * 4 + (threadIdx.x >> 6);   // 0..767
    int lane = threadIdx.x & 63;
    int l  = wid >> 8, kt = (wid >> 4) & 15, ct = wid & 15;
    int n  = ct * 16 + (lane & 15);
    int k0 = kt * 32 + (lane >> 4) * 8;
    const float* src = C + ((size_t)l * NK + n) * ND + k0;
    float4 xa = *reinterpret_cast<const float4*>(src);
    float4 xb = *reinterpret_cast<const float4*>(src + 4);
    float x[8] = {xa.x, xa.y, xa.z, xa.w, xb.x, xb.y, xb.z, xb.w};
    unsigned hp[4];
    #pragma unroll
    for (int q = 0; q < 4; ++q) {
        u16 h0 = f2bf(x[2*q]), h1 = f2bf(x[2*q+1]);
        hp[q] = (unsigned)h0 | ((unsigned)h1 << 16);
    }
    uint4 hv = {hp[0], hp[1], hp[2], hp[3]};
    int TI = kt * 48 + l * 16 + ct;
    *reinterpret_cast<uint4*>(wsu + BGH_OFF_US + (size_t)TI * 512 + lane * 8) = hv;
}

// ---------------------------------------------------------------------------
// Gram matrices (fp32 exact): block per (p, i), thread j -> G_p[i][j]
__global__ __launch_bounds__(256) void gram_kernel(const float* __restrict__ C,
                                                   float* __restrict__ ws) {
    int p = blockIdx.x >> 8;       // 0:(0,1) 1:(0,2) 2:(1,2)
    int i = blockIdx.x & 255;
    int a = (p == 2) ? 1 : 0;
    int b = (p == 0) ? 1 : 2;
    __shared__ float Ca[512];
    float2 v = *reinterpret_cast<const float2*>(C + ((size_t)a * NK + i) * ND + threadIdx.x * 2);
    Ca[threadIdx.x * 2]     = v.x;
    Ca[threadIdx.x * 2 + 1] = v.y;
    __syncthreads();
    int j = threadIdx.x;
    const float* Cb = C + ((size_t)b * NK + j) * ND;
    float s = 0.f;
    for (int d = 0; d < 512; d += 8) {
        float4 u = *reinterpret_cast<const float4*>(Cb + d);
        float4 w = *reinterpret_cast<const float4*>(Cb + d + 4);
        s = fmaf(u.x, Ca[d+0], s); s = fmaf(u.y, Ca[d+1], s);
        s = fmaf(u.z, Ca[d+2], s); s = fmaf(u.w, Ca[d+3], s);
        s = fmaf(w.x, Ca[d+4], s); s = fmaf(w.y, Ca[d+5], s);
        s = fmaf(w.z, Ca[d+6], s); s = fmaf(w.w, Ca[d+7], s);
    }
    float* G = ws + ((p == 0) ? G01_OFF : (p == 1) ? G02_OFF : G12_OFF);
    G[(size_t)i * NK + j] = s;
}

// ---------------------------------------------------------------------------
// Main: 64 rows x 768 cols per block; 8 waves = 2 row-groups x 4 col-groups.
// Barrier-free MFMA loop: B frags straight from L2, A frags converted in-reg.
__global__ __launch_bounds__(512, 2) void rq_fused(const float* __restrict__ X,
                                                   const float* __restrict__ C,
                                                   const float* __restrict__ ws,
                                                   const u16* __restrict__ wsu,
                                                   float* __restrict__ out) {
    __shared__ float redV[4][64];
    __shared__ int   redI[4][64];
    __shared__ float mrow[64];
    __shared__ int   iseltmp[64];
    __shared__ int   isel[3][64];      // LOCAL ids 0..255
    __shared__ int   ccnt[64];
    __shared__ int   ntask;
    __shared__ int   taskRC[256];      // (row<<10)|global_col
    __shared__ float taskS[256];

    const int tid  = threadIdx.x;
    const int w    = tid >> 6;          // 0..7
    const int lane = tid & 63;
    const int wr   = w >> 2;            // row-group 0..1 (32 rows each)
    const int wc   = w & 3;             // col-group 0..3
    const int hi4  = lane >> 4, l15 = lane & 15;
    const int row0 = blockIdx.x * TM;

    const float* csq = ws + CSQ_OFF;
    const float* G01 = ws + G01_OFF;
    const float* G02 = ws + G02_OFF;
    const float* G12 = ws + G12_OFF;

    f4 acc[2][12];
    #pragma unroll
    for (int rtl = 0; rtl < 2; ++rtl)
        #pragma unroll
        for (int j = 0; j < 12; ++j) acc[rtl][j] = (f4){0.f, 0.f, 0.f, 0.f};

    // ---- main GEMM loop (no barriers, no LDS) ----
    const float* x0 = X + (size_t)(row0 + wr * 32 + l15) * ND + hi4 * 8;
    const u16*   Bg = wsu + BGH_OFF_US + lane * 8;

    #pragma unroll 2
    for (int kt = 0; kt < 16; ++kt) {
        s8v a[2];
        #pragma unroll
        for (int rtl = 0; rtl < 2; ++rtl) {
            const float* xp = x0 + (size_t)rtl * 16 * ND + kt * 32;
            float4 xa = *reinterpret_cast<const float4*>(xp);
            float4 xb = *reinterpret_cast<const float4*>(xp + 4);
            s8v t;
            t[0] = (short)f2bf(xa.x); t[1] = (short)f2bf(xa.y);
            t[2] = (short)f2bf(xa.z); t[3] = (short)f2bf(xa.w);
            t[4] = (short)f2bf(xb.x); t[5] = (short)f2bf(xb.y);
            t[6] = (short)f2bf(xb.w == xb.w ? xb.z : xb.z); // keep simple: z
            t[6] = (short)f2bf(xb.z);
            t[7] = (short)f2bf(xb.w);
            a[rtl] = t;
        }
        const u16* bk = Bg + (size_t)kt * (48 * 512);
        #pragma unroll
        for (int j = 0; j < 12; ++j) {
            s8v b = *reinterpret_cast<const s8v*>(bk + (size_t)(wc + 4 * j) * 512);
            acc[0][j] = __builtin_amdgcn_mfma_f32_16x16x32_bf16(a[0], b, acc[0][j], 0, 0, 0);
            acc[1][j] = __builtin_amdgcn_mfma_f32_16x16x32_bf16(a[1], b, acc[1][j], 0, 0, 0);
        }
    }

    // ---- cascade: per-layer score transform + argmin + exact refine ----
    #pragma unroll
    for (int l = 0; l < NL; ++l) {
        if (tid < 64) ccnt[tid] = 0;
        if (tid == 0) ntask = 0;

        // in-place acc -> score, track per-row local min
        float bv[2][4]; int bi[2][4];
        #pragma unroll
        for (int rtl = 0; rtl < 2; ++rtl)
            #pragma unroll
            for (int reg = 0; reg < 4; ++reg) { bv[rtl][reg] = 3.4e38f; bi[rtl][reg] = 0x7fffffff; }

        #pragma unroll
        for (int rtl = 0; rtl < 2; ++rtl)
            #pragma unroll
            for (int f = 0; f < 4; ++f) {
                const int j  = 4 * l + f;
                const int lc = (wc + 4 * f) * 16 + l15;
                const int gc = l * 256 + lc;
                const float cs = csq[gc];
                #pragma unroll
                for (int reg = 0; reg < 4; ++reg) {
                    const int row = wr * 32 + rtl * 16 + hi4 * 4 + reg;
                    float s = cs - 2.f * acc[rtl][j][reg];
                    if (l == 1) {
                        s += 2.f * G01[(size_t)isel[0][row] * NK + lc];
                    }
                    if (l == 2) {
                        s += 2.f * (G02[(size_t)isel[0][row] * NK + lc] +
                                    G12[(size_t)isel[1][row] * NK + lc]);
                    }
                    acc[rtl][j][reg] = s;
                    if (s < bv[rtl][reg] || (s == bv[rtl][reg] && gc < bi[rtl][reg])) {
                        bv[rtl][reg] = s; bi[rtl][reg] = gc;
                    }
                }
            }
        // reduce over the 16 cols held by the 16-lane group
        #pragma unroll
        for (int rtl = 0; rtl < 2; ++rtl)
            #pragma unroll
            for (int reg = 0; reg < 4; ++reg) {
                float v = bv[rtl][reg]; int ix = bi[rtl][reg];
                #pragma unroll
                for (int m = 1; m < 16; m <<= 1) {
                    float v2 = __shfl_xor(v, m, 64);
                    int   i2 = __shfl_xor(ix, m, 64);
                    if (v2 < v || (v2 == v && i2 < ix)) { v = v2; ix = i2; }
                }
                if (l15 == 0) {
                    int row = wr * 32 + rtl * 16 + hi4 * 4 + reg;
                    redV[wc][row] = v; redI[wc][row] = ix;
                }
            }
        __syncthreads();
        if (tid < 64) {
            float v = redV[0][tid]; int ix = redI[0][tid];
            #pragma unroll
            for (int q = 1; q < 4; ++q) {
                float v2 = redV[q][tid]; int i2 = redI[q][tid];
                if (v2 < v || (v2 == v && i2 < ix)) { v = v2; ix = i2; }
            }
            mrow[tid] = v; iseltmp[tid] = ix;
        }
        __syncthreads();
        // pass 1: count near-ties per row
        #pragma unroll
        for (int rtl = 0; rtl < 2; ++rtl)
            #pragma unroll
            for (int f = 0; f < 4; ++f) {
                const int j = 4 * l + f;
                #pragma unroll
                for (int reg = 0; reg < 4; ++reg) {
                    const int row = wr * 32 + rtl * 16 + hi4 * 4 + reg;
                    if (acc[rtl][j][reg] <= mrow[row] + DELTA)
                        atomicAdd(&ccnt[row], 1);
                }
            }
        __syncthreads();
        // pass 2: append candidates only for contested rows
        #pragma unroll
        for (int rtl = 0; rtl < 2; ++rtl)
            #pragma unroll
            for (int f = 0; f < 4; ++f) {
                const int j  = 4 * l + f;
                const int lc = (wc + 4 * f) * 16 + l15;
                const int gc = l * 256 + lc;
                #pragma unroll
                for (int reg = 0; reg < 4; ++reg) {
                    const int row = wr * 32 + rtl * 16 + hi4 * 4 + reg;
                    if (ccnt[row] >= 2 && acc[rtl][j][reg] <= mrow[row] + DELTA) {
                        int t = atomicAdd(&ntask, 1);
                        if (t < 256) taskRC[t] = (row << 10) | gc;
                    }
                }
            }
        __syncthreads();
        // exact fp32 rescore of contested candidates (one wave per task)
        {
            int nt = ntask < 256 ? ntask : 256;
            for (int ti = w; ti < nt; ti += 8) {
                int rc = taskRC[ti];
                int trow = rc >> 10, gcol = rc & 1023;
                const float* xr = X + (size_t)(row0 + trow) * ND + lane * 8;
                const float* cr = C + (size_t)gcol * ND + lane * 8;
                float4 xa = *reinterpret_cast<const float4*>(xr);
                float4 xb = *reinterpret_cast<const float4*>(xr + 4);
                float4 ca = *reinterpret_cast<const float4*>(cr);
                float4 cb = *reinterpret_cast<const float4*>(cr + 4);
                float d = xa.x*ca.x + xa.y*ca.y + xa.z*ca.z + xa.w*ca.w
                        + xb.x*cb.x + xb.y*cb.y + xb.z*cb.z + xb.w*cb.w;
                #pragma unroll
                for (int m = 1; m < 64; m <<= 1) d += __shfl_xor(d, m, 64);
                if (lane == 0) {
                    int lc2 = gcol & 255;
                    float sc = csq[gcol] - 2.f * d;
                    if (l == 1) sc += 2.f * G01[(size_t)isel[0][trow] * NK + lc2];
                    if (l == 2) sc += 2.f * (G02[(size_t)isel[0][trow] * NK + lc2] +
                                             G12[(size_t)isel[1][trow] * NK + lc2]);
                    taskS[ti] = sc;
                }
            }
        }
        __syncthreads();
        if (tid < 64) {
            int best = iseltmp[tid];
            if (ccnt[tid] >= 2) {
                float bvv = 3.4e38f; int bii = 0x7fffffff;
                int nt = ntask < 256 ? ntask : 256;
                for (int t = 0; t < nt; ++t) {
                    int rc = taskRC[t];
                    if ((rc >> 10) == tid) {
                        float s = taskS[t]; int c = rc & 1023;
                        if (s < bvv || (s == bvv && c < bii)) { bvv = s; bii = c; }
                    }
                }
                best = bii;
            }
            isel[l][tid] = best & 255;
        }
        __syncthreads();
    }

    // ---- outputs ----
    if (tid < TM * 3) {
        int r = tid / 3, l = tid % 3;
        out[(size_t)(row0 + r) * 3 + l] = (float)isel[l][r];
    }
    float* rec = out + (size_t)ROWS * 3;
    #pragma unroll
    for (int q = 0; q < 16; ++q) {
        int idx = tid + 512 * q;          // 0..8191
        int r   = idx >> 7;               // 0..63
        int d4  = (idx & 127) * 4;
        float4 v0 = *reinterpret_cast<const float4*>(C + ((size_t)(  0 + isel[0][r])) * ND + d4);
        float4 v1 = *reinterpret_cast<const float4*>(C + ((size_t)(256 + isel[1][r])) * ND + d4);
        float4 v2 = *reinterpret_cast<const float4*>(C + ((size_t)(512 + isel[2][r])) * ND + d4);
        float4 o;
        o.x = v0.x + v1.x + v2.x;
        o.y = v0.y + v1.y + v2.y;
        o.z = v0.z + v1.z + v2.z;
        o.w = v0.w + v1.w + v2.w;
        *reinterpret_cast<float4*>(rec + (size_t)(row0 + r) * ND + d4) = o;
    }
}

// ---------------------------------------------------------------------------
extern "C" void kernel_launch(void* const* d_in, const int* in_sizes, int n_in,
                              void* d_out, int out_size, void* d_ws, size_t ws_size,
                              hipStream_t stream) {
    const float* X  = (const float*)d_in[0];   // [128,1024,512]
    const float* C  = (const float*)d_in[1];   // [3,256,512]
    float* ws  = (float*)d_ws;
    u16*   wsu = (u16*)d_ws;
    float* out = (float*)d_out;

    hipLaunchKernelGGL(prep_csq,    dim3(192),       dim3(256), 0, stream, C, ws);
    hipLaunchKernelGGL(prep_b,      dim3(192),       dim3(256), 0, stream, C, wsu);
    hipLaunchKernelGGL(gram_kernel, dim3(768),       dim3(256), 0, stream, C, ws);
    hipLaunchKernelGGL(rq_fused,    dim3(ROWS / TM), dim3(512), 0, stream,
                       X, C, ws, wsu, out);
}

// Round 4
// 529.752 us; speedup vs baseline: 2.5529x; 1.6444x over previous
//
#include <hip/hip_runtime.h>

typedef unsigned short u16;
typedef unsigned int u32;
typedef short s8v __attribute__((ext_vector_type(8)));   // 8 bf16 in 4 VGPRs
typedef float f4  __attribute__((ext_vector_type(4)));   // MFMA acc

constexpr int ND = 512, NL = 3, NK = 256;
constexpr int ROWS = 128 * 1024;
#define TM 64
#define DELTA 0.75f

// ---- workspace layout ----
constexpr int CSQ_OFF = 0;                    // 768 floats
constexpr int G01_OFF = 1024;
constexpr int G02_OFF = G01_OFF + 65536;
constexpr int G12_OFF = G02_OFF + 65536;
constexpr int WS_FLOATS = G12_OFF + 65536;    // 197632 floats
// bf16 fragment table: [kt=16][ct_g=48][512 ushorts] (1KB tiles, kt-major)
constexpr int BGH_OFF_US = WS_FLOATS * 2;     // ushort offset
// total bytes = 197632*4 + 768*512*2 = 1.58 MB

__device__ __forceinline__ u16 f2bf(float f) {          // fp32 -> bf16 RNE
    unsigned u = __float_as_uint(f);
    return (u16)((u + 0x7fffu + ((u >> 16) & 1u)) >> 16);
}

// ---------------------------------------------------------------------------
__global__ __launch_bounds__(256) void prep_csq(const float* __restrict__ C,
                                                float* __restrict__ ws) {
    int wid  = blockIdx.x * 4 + (threadIdx.x >> 6);   // 0..767
    int lane = threadIdx.x & 63;
    const float4* src = reinterpret_cast<const float4*>(C + (size_t)wid * ND + lane * 8);
    float4 a = src[0], b = src[1];
    float sq = a.x*a.x + a.y*a.y + a.z*a.z + a.w*a.w
             + b.x*b.x + b.y*b.y + b.z*b.z + b.w*b.w;
    #pragma unroll
    for (int m = 1; m < 64; m <<= 1) sq += __shfl_xor(sq, m, 64);
    if (lane == 0) ws[CSQ_OFF + wid] = sq;
}

// ---------------------------------------------------------------------------
// B fragment table: bf16 MFMA B-frag layout, kt-major. TI = kt*48 + l*16 + ct
// lane slot: col = ct*16 + (lane&15), k = kt*32 + (lane>>4)*8 + j (j=0..7)
__global__ __launch_bounds__(256) void prep_b(const float* __restrict__ C,
                                              u16* __restrict__ wsu) {
    int wid  = blockIdx.x * 4 + (threadIdx.x >> 6);   // 0..767
    int lane = threadIdx.x & 63;
    int l  = wid >> 8, kt = (wid >> 4) & 15, ct = wid & 15;
    int n  = ct * 16 + (lane & 15);
    int k0 = kt * 32 + (lane >> 4) * 8;
    const float* src = C + ((size_t)l * NK + n) * ND + k0;
    float4 xa = *reinterpret_cast<const float4*>(src);
    float4 xb = *reinterpret_cast<const float4*>(src + 4);
    float x[8] = {xa.x, xa.y, xa.z, xa.w, xb.x, xb.y, xb.z, xb.w};
    unsigned hp[4];
    #pragma unroll
    for (int q = 0; q < 4; ++q) {
        u16 h0 = f2bf(x[2*q]), h1 = f2bf(x[2*q+1]);
        hp[q] = (unsigned)h0 | ((unsigned)h1 << 16);
    }
    uint4 hv = {hp[0], hp[1], hp[2], hp[3]};
    int TI = kt * 48 + l * 16 + ct;
    *reinterpret_cast<uint4*>(wsu + BGH_OFF_US + (size_t)TI * 512 + lane * 8) = hv;
}

// ---------------------------------------------------------------------------
__global__ __launch_bounds__(256) void gram_kernel(const float* __restrict__ C,
                                                   float* __restrict__ ws) {
    int p = blockIdx.x >> 8;       // 0:(0,1) 1:(0,2) 2:(1,2)
    int i = blockIdx.x & 255;
    int a = (p == 2) ? 1 : 0;
    int b = (p == 0) ? 1 : 2;
    __shared__ float Ca[512];
    float2 v = *reinterpret_cast<const float2*>(C + ((size_t)a * NK + i) * ND + threadIdx.x * 2);
    Ca[threadIdx.x * 2]     = v.x;
    Ca[threadIdx.x * 2 + 1] = v.y;
    __syncthreads();
    int j = threadIdx.x;
    const float* Cb = C + ((size_t)b * NK + j) * ND;
    float s = 0.f;
    for (int d = 0; d < 512; d += 8) {
        float4 u = *reinterpret_cast<const float4*>(Cb + d);
        float4 w = *reinterpret_cast<const float4*>(Cb + d + 4);
        s = fmaf(u.x, Ca[d+0], s); s = fmaf(u.y, Ca[d+1], s);
        s = fmaf(u.z, Ca[d+2], s); s = fmaf(u.w, Ca[d+3], s);
        s = fmaf(w.x, Ca[d+4], s); s = fmaf(w.y, Ca[d+5], s);
        s = fmaf(w.z, Ca[d+6], s); s = fmaf(w.w, Ca[d+7], s);
    }
    float* G = ws + ((p == 0) ? G01_OFF : (p == 1) ? G02_OFF : G12_OFF);
    G[(size_t)i * NK + j] = s;
}

// ---------------------------------------------------------------------------
// Main: 64 rows x 768 cols per block; 1024 threads = 16 waves.
// wave (wr = w>>3, wc = w&7): rows wr*32..+31 (2 rt tiles), cols ct_g = wc+8f.
// A staged to LDS (double buffer, frag order); B direct from L2, reg dbuf.
__global__ __launch_bounds__(1024, 4) void rq_fused(const float* __restrict__ X,
                                                    const float* __restrict__ C,
                                                    const float* __restrict__ ws,
                                                    const u16* __restrict__ wsu,
                                                    float* __restrict__ out) {
    __shared__ __align__(16) u16 Abuf[2][4 * 512];   // 8KB: 4 rt tiles in frag order
    __shared__ float redV[8][64];
    __shared__ int   redI[8][64];
    __shared__ float mrow[64];
    __shared__ int   iseltmp[64];
    __shared__ int   isel[3][64];
    __shared__ int   ccnt[64];
    __shared__ int   ntask;
    __shared__ int   taskRC[256];
    __shared__ float taskS[256];

    const int tid  = threadIdx.x;
    const int w    = tid >> 6;          // 0..15
    const int lane = tid & 63;
    const int wr   = w >> 3;            // 0..1
    const int wc   = w & 7;             // 0..7
    const int hi4  = lane >> 4, l15 = lane & 15;
    const int row0 = blockIdx.x * TM;

    const float* csq = ws + CSQ_OFF;
    const float* G01 = ws + G01_OFF;
    const float* G02 = ws + G02_OFF;
    const float* G12 = ws + G12_OFF;

    f4 acc[2][6];
    #pragma unroll
    for (int rt = 0; rt < 2; ++rt)
        #pragma unroll
        for (int f = 0; f < 6; ++f) acc[rt][f] = (f4){0.f, 0.f, 0.f, 0.f};

    // ---- staging geometry ----
    // thread t covers u16 pair idx = 2t: tile rt4 = idx>>9, pos = idx&511,
    // frag lane ln = pos>>3, j = pos&7 (even) -> row = ln&15, k = (ln>>4)*8+j
    const int sidx = tid * 2;
    const int srt4 = sidx >> 9;
    const int spos = sidx & 511;
    const int sln  = spos >> 3;
    const int sj   = spos & 7;
    const float* xsrc = X + (size_t)(row0 + srt4 * 16 + (sln & 15)) * ND
                          + (sln >> 4) * 8 + sj;
    u32* const abuf32_0 = reinterpret_cast<u32*>(&Abuf[0][0]);
    u32* const abuf32_1 = reinterpret_cast<u32*>(&Abuf[1][0]);

    const u16* Bbase = wsu + BGH_OFF_US + (size_t)wc * 512 + lane * 8;

    #define XFETCH(kt) (*reinterpret_cast<const float2*>(xsrc + (kt) * 32))
    #define XCOMMIT(v, buf) { (buf)[tid] = (u32)f2bf((v).x) | ((u32)f2bf((v).y) << 16); }
    #define BLOAD(dst, kt)                                                        \
        { const u16* bp = Bbase + (size_t)(kt) * (48 * 512);                      \
          _Pragma("unroll")                                                       \
          for (int f = 0; f < 6; ++f)                                             \
              dst[f] = *reinterpret_cast<const s8v*>(bp + f * 8 * 512); }
    #define ACONSUME(buf, bfr)                                                    \
        { s8v a0 = *reinterpret_cast<const s8v*>(&Abuf[buf][(wr * 2 + 0) * 512 + lane * 8]); \
          s8v a1 = *reinterpret_cast<const s8v*>(&Abuf[buf][(wr * 2 + 1) * 512 + lane * 8]); \
          _Pragma("unroll")                                                       \
          for (int f = 0; f < 6; ++f) {                                           \
              acc[0][f] = __builtin_amdgcn_mfma_f32_16x16x32_bf16(a0, bfr[f], acc[0][f], 0, 0, 0); \
              acc[1][f] = __builtin_amdgcn_mfma_f32_16x16x32_bf16(a1, bfr[f], acc[1][f], 0, 0, 0); \
          } }

    // ---- software-pipelined main loop ----
    s8v bcur[6], bnxt[6];
    float2 xv = XFETCH(0);
    BLOAD(bcur, 0);
    XCOMMIT(xv, abuf32_0);
    xv = XFETCH(1);
    __syncthreads();

    #pragma unroll 1
    for (int kt = 0; kt < 16; kt += 2) {
        // even: consume buf0 + bcur
        XCOMMIT(xv, abuf32_1);
        BLOAD(bnxt, kt + 1);
        if (kt + 2 < 16) xv = XFETCH(kt + 2);
        ACONSUME(0, bcur);
        __syncthreads();
        // odd: consume buf1 + bnxt
        if (kt + 2 < 16) {
            XCOMMIT(xv, abuf32_0);
            BLOAD(bcur, kt + 2);
            if (kt + 3 < 16) xv = XFETCH(kt + 3);
        }
        ACONSUME(1, bnxt);
        __syncthreads();
    }

    // ---- cascade: per-layer score transform + argmin + exact refine ----
    #pragma unroll
    for (int l = 0; l < NL; ++l) {
        if (tid < 64) ccnt[tid] = 0;
        if (tid == 0) ntask = 0;

        float bv[2][4]; int bi[2][4];
        #pragma unroll
        for (int rt = 0; rt < 2; ++rt)
            #pragma unroll
            for (int reg = 0; reg < 4; ++reg) { bv[rt][reg] = 3.4e38f; bi[rt][reg] = 0x7fffffff; }

        #pragma unroll
        for (int rt = 0; rt < 2; ++rt)
            #pragma unroll
            for (int e = 0; e < 2; ++e) {
                const int f  = 2 * l + e;
                const int lc = (wc + 8 * e) * 16 + l15;     // col within layer
                const int gc = l * 256 + lc;                // global col
                const float cs = csq[gc];
                #pragma unroll
                for (int reg = 0; reg < 4; ++reg) {
                    const int row = wr * 32 + rt * 16 + hi4 * 4 + reg;
                    float s = cs - 2.f * acc[rt][f][reg];
                    if (l == 1) s += 2.f * G01[(size_t)isel[0][row] * NK + lc];
                    if (l == 2) s += 2.f * (G02[(size_t)isel[0][row] * NK + lc] +
                                            G12[(size_t)isel[1][row] * NK + lc]);
                    acc[rt][f][reg] = s;
                    if (s < bv[rt][reg] || (s == bv[rt][reg] && gc < bi[rt][reg])) {
                        bv[rt][reg] = s; bi[rt][reg] = gc;
                    }
                }
            }
        #pragma unroll
        for (int rt = 0; rt < 2; ++rt)
            #pragma unroll
            for (int reg = 0; reg < 4; ++reg) {
                float v = bv[rt][reg]; int ix = bi[rt][reg];
                #pragma unroll
                for (int m = 1; m < 16; m <<= 1) {
                    float v2 = __shfl_xor(v, m, 64);
                    int   i2 = __shfl_xor(ix, m, 64);
                    if (v2 < v || (v2 == v && i2 < ix)) { v = v2; ix = i2; }
                }
                if (l15 == 0) {
                    int row = wr * 32 + rt * 16 + hi4 * 4 + reg;
                    redV[wc][row] = v; redI[wc][row] = ix;
                }
            }
        __syncthreads();
        if (tid < 64) {
            float v = redV[0][tid]; int ix = redI[0][tid];
            #pragma unroll
            for (int q = 1; q < 8; ++q) {
                float v2 = redV[q][tid]; int i2 = redI[q][tid];
                if (v2 < v || (v2 == v && i2 < ix)) { v = v2; ix = i2; }
            }
            mrow[tid] = v; iseltmp[tid] = ix;
        }
        __syncthreads();
        // pass 1: count near-ties per row
        #pragma unroll
        for (int rt = 0; rt < 2; ++rt)
            #pragma unroll
            for (int e = 0; e < 2; ++e) {
                const int f = 2 * l + e;
                #pragma unroll
                for (int reg = 0; reg < 4; ++reg) {
                    const int row = wr * 32 + rt * 16 + hi4 * 4 + reg;
                    if (acc[rt][f][reg] <= mrow[row] + DELTA)
                        atomicAdd(&ccnt[row], 1);
                }
            }
        __syncthreads();
        // pass 2: append candidates for contested rows
        #pragma unroll
        for (int rt = 0; rt < 2; ++rt)
            #pragma unroll
            for (int e = 0; e < 2; ++e) {
                const int f  = 2 * l + e;
                const int lc = (wc + 8 * e) * 16 + l15;
                const int gc = l * 256 + lc;
                #pragma unroll
                for (int reg = 0; reg < 4; ++reg) {
                    const int row = wr * 32 + rt * 16 + hi4 * 4 + reg;
                    if (ccnt[row] >= 2 && acc[rt][f][reg] <= mrow[row] + DELTA) {
                        int t = atomicAdd(&ntask, 1);
                        if (t < 256) taskRC[t] = (row << 10) | gc;
                    }
                }
            }
        __syncthreads();
        // exact fp32 rescore (one wave per task)
        {
            int nt = ntask < 256 ? ntask : 256;
            for (int ti = w; ti < nt; ti += 16) {
                int rc = taskRC[ti];
                int trow = rc >> 10, gcol = rc & 1023;
                const float* xr = X + (size_t)(row0 + trow) * ND + lane * 8;
                const float* cr = C + (size_t)gcol * ND + lane * 8;
                float4 xa = *reinterpret_cast<const float4*>(xr);
                float4 xb = *reinterpret_cast<const float4*>(xr + 4);
                float4 ca = *reinterpret_cast<const float4*>(cr);
                float4 cb = *reinterpret_cast<const float4*>(cr + 4);
                float d = xa.x*ca.x + xa.y*ca.y + xa.z*ca.z + xa.w*ca.w
                        + xb.x*cb.x + xb.y*cb.y + xb.z*cb.z + xb.w*cb.w;
                #pragma unroll
                for (int m = 1; m < 64; m <<= 1) d += __shfl_xor(d, m, 64);
                if (lane == 0) {
                    int lc2 = gcol & 255;
                    float sc = csq[gcol] - 2.f * d;
                    if (l == 1) sc += 2.f * G01[(size_t)isel[0][trow] * NK + lc2];
                    if (l == 2) sc += 2.f * (G02[(size_t)isel[0][trow] * NK + lc2] +
                                             G12[(size_t)isel[1][trow] * NK + lc2]);
                    taskS[ti] = sc;
                }
            }
        }
        __syncthreads();
        if (tid < 64) {
            int best = iseltmp[tid];
            if (ccnt[tid] >= 2) {
                float bvv = 3.4e38f; int bii = 0x7fffffff;
                int nt = ntask < 256 ? ntask : 256;
                for (int t = 0; t < nt; ++t) {
                    int rc = taskRC[t];
                    if ((rc >> 10) == tid) {
                        float s = taskS[t]; int c = rc & 1023;
                        if (s < bvv || (s == bvv && c < bii)) { bvv = s; bii = c; }
                    }
                }
                best = bii;
            }
            isel[l][tid] = best & 255;
        }
        __syncthreads();
    }

    // ---- outputs ----
    if (tid < TM * 3) {
        int r = tid / 3, l = tid % 3;
        out[(size_t)(row0 + r) * 3 + l] = (float)isel[l][r];
    }
    float* rec = out + (size_t)ROWS * 3;
    #pragma unroll
    for (int q = 0; q < 8; ++q) {
        int idx = tid + 1024 * q;         // 0..8191
        int r   = idx >> 7;               // 0..63
        int d4  = (idx & 127) * 4;
        float4 v0 = *reinterpret_cast<const float4*>(C + ((size_t)(  0 + isel[0][r])) * ND + d4);
        float4 v1 = *reinterpret_cast<const float4*>(C + ((size_t)(256 + isel[1][r])) * ND + d4);
        float4 v2 = *reinterpret_cast<const float4*>(C + ((size_t)(512 + isel[2][r])) * ND + d4);
        float4 o;
        o.x = v0.x + v1.x + v2.x;
        o.y = v0.y + v1.y + v2.y;
        o.z = v0.z + v1.z + v2.z;
        o.w = v0.w + v1.w + v2.w;
        *reinterpret_cast<float4*>(rec + (size_t)(row0 + r) * ND + d4) = o;
    }
}

// ---------------------------------------------------------------------------
extern "C" void kernel_launch(void* const* d_in, const int* in_sizes, int n_in,
                              void* d_out, int out_size, void* d_ws, size_t ws_size,
                              hipStream_t stream) {
    const float* X  = (const float*)d_in[0];   // [128,1024,512]
    const float* C  = (const float*)d_in[1];   // [3,256,512]
    float* ws  = (float*)d_ws;
    u16*   wsu = (u16*)d_ws;
    float* out = (float*)d_out;

    hipLaunchKernelGGL(prep_csq,    dim3(192),       dim3(256),  0, stream, C, ws);
    hipLaunchKernelGGL(prep_b,      dim3(192),       dim3(256),  0, stream, C, wsu);
    hipLaunchKernelGGL(gram_kernel, dim3(768),       dim3(256),  0, stream, C, ws);
    hipLaunchKernelGGL(rq_fused,    dim3(ROWS / TM), dim3(1024), 0, stream,
                       X, C, ws, wsu, out);
}